// Round 5
// baseline (232.323 us; speedup 1.0000x reference)
//
#include <hip/hip_runtime.h>
#include <hip/hip_bf16.h>

#define D_MODEL 1280
#define NUM_EXPERTS 20
#define HEAD_DIM 64
#define SEQ 1024
#define BATCH 4
#define BS_TOK 4096
#define QKV_N 192
#define QKV_W 3840   // 20 experts * 192, flat qkv row width

typedef __attribute__((ext_vector_type(8))) short short8;
typedef __attribute__((ext_vector_type(4))) float f32x4;
typedef __hip_bfloat16 bf16;

static __device__ __forceinline__ void gload_lds16(const void* g, void* l) {
  __builtin_amdgcn_global_load_lds((const __attribute__((address_space(1))) void*)g,
                                   (__attribute__((address_space(3))) void*)l, 16, 0, 0);
}

// ---------------- router_w [D][E] f32 -> rwT [E][D] f32 ----------------
__global__ __launch_bounds__(256) void k_rwT(const float* __restrict__ in,
                                             float* __restrict__ out) {
  int i = blockIdx.x * 256 + threadIdx.x;
  if (i < D_MODEL * NUM_EXPERTS) {
    int d = i / NUM_EXPERTS, e = i % NUM_EXPERTS;
    out[e * D_MODEL + d] = in[i];
  }
}

// ---------------- router gates + x -> bf16 (4 rows/block, wave per row) ----
__global__ __launch_bounds__(256) void k_gates(const float* __restrict__ x,
    const float* __restrict__ rwT, const float* __restrict__ rb,
    float* __restrict__ gates, bf16* __restrict__ xb)
{
  __shared__ float xs[4][D_MODEL];
  __shared__ float logits[4][NUM_EXPERTS];
  const int r0 = blockIdx.x * 4;
  for (int i = threadIdx.x; i < 4 * (D_MODEL / 2); i += 256) {
    int r = i / (D_MODEL / 2), d2 = (i % (D_MODEL / 2)) * 2;
    float2 v = *(const float2*)(x + (size_t)(r0 + r) * D_MODEL + d2);
    xs[r][d2] = v.x; xs[r][d2 + 1] = v.y;
    __hip_bfloat162 h;
    h.x = __float2bfloat16(v.x); h.y = __float2bfloat16(v.y);
    *(__hip_bfloat162*)(xb + (size_t)(r0 + r) * D_MODEL + d2) = h;
  }
  __syncthreads();
  const int wid = threadIdx.x >> 6, lane = threadIdx.x & 63;
  for (int e = 0; e < NUM_EXPERTS; ++e) {
    float s = 0.f;
    #pragma unroll
    for (int j = 0; j < D_MODEL / 64; ++j) {
      int d = lane + 64 * j;
      s += xs[wid][d] * rwT[e * D_MODEL + d];
    }
    #pragma unroll
    for (int m = 32; m >= 1; m >>= 1) s += __shfl_xor(s, m);
    if (lane == 0) logits[wid][e] = s + rb[e];
  }
  __syncthreads();
  if (lane < 32) {
    float v = (lane < NUM_EXPERTS) ? logits[wid][lane] : -1e30f;
    float mx = v;
    #pragma unroll
    for (int m = 16; m >= 1; m >>= 1) mx = fmaxf(mx, __shfl_xor(mx, m, 32));
    float p = (lane < NUM_EXPERTS) ? __expf(v - mx) : 0.f;
    float sum = p;
    #pragma unroll
    for (int m = 16; m >= 1; m >>= 1) sum += __shfl_xor(sum, m, 32);
    if (lane < NUM_EXPERTS)
      gates[(size_t)(r0 + wid) * NUM_EXPERTS + lane] = p / sum;
  }
}

// ---------------- f32 [batch][R][C] -> bf16 [batch][C][R] ----------------
__global__ __launch_bounds__(256) void k_transpose(const float* __restrict__ in,
    bf16* __restrict__ out, int R, int C)
{
  __shared__ float tile[32][33];
  const size_t bo = (size_t)blockIdx.z * R * C;
  const int c0 = blockIdx.x * 32, r0 = blockIdx.y * 32;
  const int tx = threadIdx.x, ty = threadIdx.y;  // block (32,8)
  #pragma unroll
  for (int i = 0; i < 4; ++i)
    tile[ty + 8*i][tx] = in[bo + (size_t)(r0 + ty + 8*i) * C + (c0 + tx)];
  __syncthreads();
  #pragma unroll
  for (int i = 0; i < 4; ++i)
    out[bo + (size_t)(c0 + ty + 8*i) * R + (r0 + tx)] =
        __float2bfloat16(tile[tx][ty + 8*i]);
}

// ------- bf16 MFMA GEMM, 128x128 tile: C = A @ BT^T + bias ----------------
// A [M,K] bf16; BT [N,K] bf16; bias [N] f32; C [M,N].
// grid = 8 XCD * 4 m-panels * NT n-panels (1D); M must be 4096 (32 m-tiles).
// XCD swizzle: xcd owns m-panels {4*xcd..4*xcd+3}, m-inner order so the
// B n-panel is reused by 4 consecutive blocks (L2-resident per XCD).
template<bool OUT_BF16>
__global__ __launch_bounds__(256) void k_gemm(
    const bf16* __restrict__ A, const bf16* __restrict__ BT,
    const float* __restrict__ bias, void* __restrict__ C,
    int M, int N, int K)
{
  __shared__ __align__(16) bf16 As[128 * 64];
  __shared__ __align__(16) bf16 Bs[128 * 64];
  const int bid = blockIdx.x;
  const int xcd = bid & 7, c = bid >> 3;
  const int m0 = (xcd * 4 + (c & 3)) * 128;
  const int n0 = (c >> 2) * 128;
  const int tid = threadIdx.x, wid = tid >> 6, lane = tid & 63;
  const int wr = wid >> 1, wc = wid & 1;
  const int fr = lane & 15, fg = lane >> 4;
  f32x4 acc[4][4] = {};
  for (int k0 = 0; k0 < K; k0 += 64) {
    #pragma unroll
    for (int p = 0; p < 4; ++p) {
      int eidx = ((p*4 + wid)*64 + lane) * 8;
      int row = eidx >> 6, col = eidx & 63;
      gload_lds16(A + (size_t)(m0 + row)*K + k0 + col, As + eidx);
      gload_lds16(BT + (size_t)(n0 + row)*K + k0 + col, Bs + eidx);
    }
    __syncthreads();
    short8 af[2][4], bfr[2][4];
    #pragma unroll
    for (int kk = 0; kk < 2; ++kk) {
      #pragma unroll
      for (int mi = 0; mi < 4; ++mi)
        af[kk][mi] = *(const short8*)(As + (wr*64 + mi*16 + fr)*64 + kk*32 + fg*8);
      #pragma unroll
      for (int ni = 0; ni < 4; ++ni)
        bfr[kk][ni] = *(const short8*)(Bs + (wc*64 + ni*16 + fr)*64 + kk*32 + fg*8);
    }
    #pragma unroll
    for (int kk = 0; kk < 2; ++kk) {
      #pragma unroll
      for (int mi = 0; mi < 4; ++mi) {
        #pragma unroll
        for (int ni = 0; ni < 4; ++ni)
          acc[mi][ni] = __builtin_amdgcn_mfma_f32_16x16x32_bf16(
              af[kk][mi], bfr[kk][ni], acc[mi][ni], 0, 0, 0);
      }
    }
    __syncthreads();
  }
  #pragma unroll
  for (int mi = 0; mi < 4; ++mi) {
    const int gr = m0 + wr*64 + mi*16 + fg*4;
    #pragma unroll
    for (int ni = 0; ni < 4; ++ni) {
      const int gc = n0 + wc*64 + ni*16 + fr;
      const float bv = bias[gc];
      #pragma unroll
      for (int r = 0; r < 4; ++r) {
        float v = acc[mi][ni][r] + bv;
        size_t off = (size_t)(gr + r) * N + gc;
        if constexpr (OUT_BF16) ((bf16*)C)[off] = __float2bfloat16(v);
        else                    ((float*)C)[off] = v;
      }
    }
  }
}

// ---------------- flash attention, conflict-free LDS (S = row>>3 ^ row&7) --
// qkv flat [BS_TOK][3840] bf16: token m, expert e -> q at e*192, k +64, v +128
// Ks/VTs: [row][8 chunks of 8 bf16]; stored chunk sc holds logical chunk
// sc ^ S(row), S(row) = ((row>>3) ^ (row&7)) & 7.  Ps: row stride 72.
#define PS_LD 72
__global__ __launch_bounds__(256) void k_attn(
    const bf16* __restrict__ qkv, const float* __restrict__ gates,
    bf16* __restrict__ combined)
{
  __shared__ __align__(16) bf16 Ks[64 * 64];
  __shared__ __align__(16) bf16 VTs[64 * 64];
  __shared__ __align__(16) bf16 Ps[4][16 * PS_LD];
  const int id = blockIdx.x;
  const int xcd = id & 7, kgrp = id >> 3;
  const int qt = kgrp / 10, bel = kgrp - qt * 10;
  const int be = xcd * 10 + bel;
  const int e = be >> 2, b = be & 3;
  const int s0 = qt * 64;
  const int tid = threadIdx.x, wid = tid >> 6, lane = tid & 63;
  const int fr = lane & 15, fg = lane >> 4;
  const bf16* base = qkv + (size_t)(b * SEQ) * QKV_W + e * QKV_N;
  short8 qf[2];
  #pragma unroll
  for (int kk = 0; kk < 2; ++kk)
    qf[kk] = *(const short8*)(base + (size_t)(s0 + wid*16 + fr) * QKV_W + kk*32 + fg*8);
  f32x4 o[4] = {};
  float Mr[4], Lr[4];
  #pragma unroll
  for (int r = 0; r < 4; ++r) { Mr[r] = -1e30f; Lr[r] = 0.f; }
  const float CSC = 0.125f * 1.44269504f;  // SCALE * log2(e)
  for (int c0 = 0; c0 < SEQ; c0 += 64) {
    // --- stage K: linear LDS dest, inverse-swizzled per-lane global src ---
    #pragma unroll
    for (int p = 0; p < 2; ++p) {
      int W = p*4 + wid;
      int row = W*8 + (lane >> 3);
      int g = (lane & 7) ^ W ^ (lane >> 3);   // sc ^ S(row)
      gload_lds16(base + (size_t)(c0 + row)*QKV_W + 64 + g*8,
                  Ks + (W*64 + lane)*8);
    }
    // --- stage V transposed; chunk swizzled by S(h) = (h>>3)^(h&7) ---
    #pragma unroll
    for (int it = 0; it < 2; ++it) {
      int key = it*32 + (tid >> 3);
      int h0b = tid & 7;                       // h>>3 for this thread
      int kc = key >> 3, ko = key & 7;
      union { short8 v; bf16 hh[8]; } u;
      u.v = *(const short8*)(base + (size_t)(c0 + key)*QKV_W + 128 + h0b*8);
      #pragma unroll
      for (int j = 0; j < 8; ++j) {
        int sc = kc ^ h0b ^ j;
        VTs[(h0b*8 + j)*64 + sc*8 + ko] = u.hh[j];
      }
    }
    __syncthreads();
    // --- QK^T ---
    f32x4 sc4[4] = {};
    #pragma unroll
    for (int kk = 0; kk < 2; ++kk) {
      #pragma unroll
      for (int ni = 0; ni < 4; ++ni) {
        int S = (ni*2 + (fr >> 3)) ^ (fr & 7);
        int cg = (kk*4 + fg) ^ S;
        short8 kf = *(const short8*)(Ks + (ni*16 + fr)*64 + cg*8);
        sc4[ni] = __builtin_amdgcn_mfma_f32_16x16x32_bf16(qf[kk], kf, sc4[ni], 0, 0, 0);
      }
    }
    // --- online softmax ---
    float Pf[4][4];
    #pragma unroll
    for (int r = 0; r < 4; ++r) {
      float mx = fmaxf(fmaxf(sc4[0][r], sc4[1][r]), fmaxf(sc4[2][r], sc4[3][r])) * CSC;
      #pragma unroll
      for (int m = 8; m >= 1; m >>= 1) mx = fmaxf(mx, __shfl_xor(mx, m));
      float Mn = fmaxf(Mr[r], mx);
      float so = exp2f(Mr[r] - Mn);
      Mr[r] = Mn;
      float ls = 0.f;
      #pragma unroll
      for (int ni = 0; ni < 4; ++ni) {
        float p = exp2f(sc4[ni][r] * CSC - Mn);
        Pf[ni][r] = p; ls += p;
      }
      #pragma unroll
      for (int m = 8; m >= 1; m >>= 1) ls += __shfl_xor(ls, m);
      Lr[r] = Lr[r] * so + ls;
      #pragma unroll
      for (int hi = 0; hi < 4; ++hi) o[hi][r] *= so;
    }
    // --- P via padded LDS ---
    #pragma unroll
    for (int r = 0; r < 4; ++r) {
      #pragma unroll
      for (int ni = 0; ni < 4; ++ni)
        Ps[wid][(fg*4 + r)*PS_LD + ni*16 + fr] = __float2bfloat16(Pf[ni][r]);
    }
    // --- PV ---
    #pragma unroll
    for (int kk = 0; kk < 2; ++kk) {
      short8 pf = *(const short8*)(&Ps[wid][fr*PS_LD + kk*32 + fg*8]);
      #pragma unroll
      for (int hi = 0; hi < 4; ++hi) {
        int S = (hi*2 + (fr >> 3)) ^ (fr & 7);
        int cg = (kk*4 + fg) ^ S;
        short8 vf = *(const short8*)(VTs + (hi*16 + fr)*64 + cg*8);
        o[hi] = __builtin_amdgcn_mfma_f32_16x16x32_bf16(pf, vf, o[hi], 0, 0, 0);
      }
    }
    __syncthreads();
  }
  const int rowb = b * SEQ + s0 + wid*16 + fg*4;
  #pragma unroll
  for (int r = 0; r < 4; ++r) {
    const float g = gates[(size_t)(rowb + r) * NUM_EXPERTS + e];
    const float inv = g / Lr[r];
    #pragma unroll
    for (int hi = 0; hi < 4; ++hi)
      combined[(size_t)(rowb + r) * D_MODEL + e*64 + hi*16 + fr] =
          __float2bfloat16(o[hi][r] * inv);
  }
}

extern "C" void kernel_launch(void* const* d_in, const int* in_sizes, int n_in,
                              void* d_out, int out_size, void* d_ws, size_t ws_size,
                              hipStream_t stream) {
  const float* x    = (const float*)d_in[0];
  const float* wqkv = (const float*)d_in[1];
  const float* bqkv = (const float*)d_in[2];
  const float* rw   = (const float*)d_in[3];
  const float* rb   = (const float*)d_in[4];
  const float* ow   = (const float*)d_in[5];
  const float* ob   = (const float*)d_in[6];
  char* ws = (char*)d_ws;
  bf16*  xb    = (bf16*)(ws);                    // 4096*1280*2      = 10485760
  bf16*  wqkvT = (bf16*)(ws + 10485760);         // [3840][1280] bf16=  9830400
  bf16*  owT   = (bf16*)(ws + 20316160);         // 1280*1280*2      =  3276800
  float* gates = (float*)(ws + 23592960);        // 4096*20*4        =   327680
  bf16*  qkv   = (bf16*)(ws + 23920640);         // [4096][3840] bf16= 31457280
  bf16*  comb  = (bf16*)(ws + 55377920);         // 4096*1280*2      = 10485760
  float* rwT   = (float*)comb;                   // aliased, consumed pre-attn

  k_rwT<<<(D_MODEL * NUM_EXPERTS + 255) / 256, 256, 0, stream>>>(rw, rwT);
  k_gates<<<1024, 256, 0, stream>>>(x, rwT, rb, gates, xb);
  // wqkvT flat rows e*192+n == [3840][1280] -> merged single QKV GEMM
  k_transpose<<<dim3(6, 40, 20), dim3(32, 8), 0, stream>>>(wqkv, wqkvT, D_MODEL, QKV_N);
  k_transpose<<<dim3(40, 40, 1), dim3(32, 8), 0, stream>>>(ow, owT, D_MODEL, D_MODEL);
  k_gemm<true><<<8 * 4 * (QKV_W / 128), 256, 0, stream>>>(xb, wqkvT, bqkv, qkv,
                                                          BS_TOK, QKV_W, D_MODEL);
  k_attn<<<1280, 256, 0, stream>>>(qkv, gates, comb);
  k_gemm<false><<<8 * 4 * (D_MODEL / 128), 256, 0, stream>>>(comb, owT, ob, d_out,
                                                             BS_TOK, D_MODEL, D_MODEL);
}

// Round 6
// 203.153 us; speedup vs baseline: 1.1436x; 1.1436x over previous
//
#include <hip/hip_runtime.h>
#include <hip/hip_bf16.h>

#define D_MODEL 1280
#define NUM_EXPERTS 20
#define HEAD_DIM 64
#define SEQ 1024
#define BATCH 4
#define BS_TOK 4096
#define QKV_N 192
#define QKV_W 3840   // 20 experts * 192, flat qkv row width

typedef __attribute__((ext_vector_type(8))) short short8;
typedef __attribute__((ext_vector_type(4))) float f32x4;
typedef __attribute__((ext_vector_type(16))) float f32x16;
typedef __hip_bfloat16 bf16;

static __device__ __forceinline__ void gload_lds16(const void* g, void* l) {
  __builtin_amdgcn_global_load_lds((const __attribute__((address_space(1))) void*)g,
                                   (__attribute__((address_space(3))) void*)l, 16, 0, 0);
}

// ---------------- router_w [D][E] f32 -> rwT [E][D] f32 ----------------
__global__ __launch_bounds__(256) void k_rwT(const float* __restrict__ in,
                                             float* __restrict__ out) {
  int i = blockIdx.x * 256 + threadIdx.x;
  if (i < D_MODEL * NUM_EXPERTS) {
    int d = i / NUM_EXPERTS, e = i % NUM_EXPERTS;
    out[e * D_MODEL + d] = in[i];
  }
}

// ---------------- router gates + x -> bf16 (4 rows/block, wave per row) ----
__global__ __launch_bounds__(256) void k_gates(const float* __restrict__ x,
    const float* __restrict__ rwT, const float* __restrict__ rb,
    float* __restrict__ gates, bf16* __restrict__ xb)
{
  __shared__ float xs[4][D_MODEL];
  __shared__ float logits[4][NUM_EXPERTS];
  const int r0 = blockIdx.x * 4;
  for (int i = threadIdx.x; i < 4 * (D_MODEL / 2); i += 256) {
    int r = i / (D_MODEL / 2), d2 = (i % (D_MODEL / 2)) * 2;
    float2 v = *(const float2*)(x + (size_t)(r0 + r) * D_MODEL + d2);
    xs[r][d2] = v.x; xs[r][d2 + 1] = v.y;
    __hip_bfloat162 h;
    h.x = __float2bfloat16(v.x); h.y = __float2bfloat16(v.y);
    *(__hip_bfloat162*)(xb + (size_t)(r0 + r) * D_MODEL + d2) = h;
  }
  __syncthreads();
  const int wid = threadIdx.x >> 6, lane = threadIdx.x & 63;
  for (int e = 0; e < NUM_EXPERTS; ++e) {
    float s = 0.f;
    #pragma unroll
    for (int j = 0; j < D_MODEL / 64; ++j) {
      int d = lane + 64 * j;
      s += xs[wid][d] * rwT[e * D_MODEL + d];
    }
    #pragma unroll
    for (int m = 32; m >= 1; m >>= 1) s += __shfl_xor(s, m);
    if (lane == 0) logits[wid][e] = s + rb[e];
  }
  __syncthreads();
  if (lane < 32) {
    float v = (lane < NUM_EXPERTS) ? logits[wid][lane] : -1e30f;
    float mx = v;
    #pragma unroll
    for (int m = 16; m >= 1; m >>= 1) mx = fmaxf(mx, __shfl_xor(mx, m, 32));
    float p = (lane < NUM_EXPERTS) ? __expf(v - mx) : 0.f;
    float sum = p;
    #pragma unroll
    for (int m = 16; m >= 1; m >>= 1) sum += __shfl_xor(sum, m, 32);
    if (lane < NUM_EXPERTS)
      gates[(size_t)(r0 + wid) * NUM_EXPERTS + lane] = p / sum;
  }
}

// ---------------- f32 [batch][R][C] -> bf16 [batch][C][R] ----------------
__global__ __launch_bounds__(256) void k_transpose(const float* __restrict__ in,
    bf16* __restrict__ out, int R, int C)
{
  __shared__ float tile[32][33];
  const size_t bo = (size_t)blockIdx.z * R * C;
  const int c0 = blockIdx.x * 32, r0 = blockIdx.y * 32;
  const int tx = threadIdx.x, ty = threadIdx.y;  // block (32,8)
  #pragma unroll
  for (int i = 0; i < 4; ++i)
    tile[ty + 8*i][tx] = in[bo + (size_t)(r0 + ty + 8*i) * C + (c0 + tx)];
  __syncthreads();
  #pragma unroll
  for (int i = 0; i < 4; ++i)
    out[bo + (size_t)(c0 + ty + 8*i) * R + (r0 + tx)] =
        __float2bfloat16(tile[tx][ty + 8*i]);
}

// ------- bf16 MFMA GEMM, 128x128 tile: C = A @ BT^T + bias ----------------
template<bool OUT_BF16>
__global__ __launch_bounds__(256) void k_gemm(
    const bf16* __restrict__ A, const bf16* __restrict__ BT,
    const float* __restrict__ bias, void* __restrict__ C,
    int M, int N, int K)
{
  __shared__ __align__(16) bf16 As[128 * 64];
  __shared__ __align__(16) bf16 Bs[128 * 64];
  const int bid = blockIdx.x;
  const int xcd = bid & 7, c = bid >> 3;
  const int m0 = (xcd * 4 + (c & 3)) * 128;
  const int n0 = (c >> 2) * 128;
  const int tid = threadIdx.x, wid = tid >> 6, lane = tid & 63;
  const int wr = wid >> 1, wc = wid & 1;
  const int fr = lane & 15, fg = lane >> 4;
  f32x4 acc[4][4] = {};
  for (int k0 = 0; k0 < K; k0 += 64) {
    #pragma unroll
    for (int p = 0; p < 4; ++p) {
      int eidx = ((p*4 + wid)*64 + lane) * 8;
      int row = eidx >> 6, col = eidx & 63;
      gload_lds16(A + (size_t)(m0 + row)*K + k0 + col, As + eidx);
      gload_lds16(BT + (size_t)(n0 + row)*K + k0 + col, Bs + eidx);
    }
    __syncthreads();
    short8 af[2][4], bfr[2][4];
    #pragma unroll
    for (int kk = 0; kk < 2; ++kk) {
      #pragma unroll
      for (int mi = 0; mi < 4; ++mi)
        af[kk][mi] = *(const short8*)(As + (wr*64 + mi*16 + fr)*64 + kk*32 + fg*8);
      #pragma unroll
      for (int ni = 0; ni < 4; ++ni)
        bfr[kk][ni] = *(const short8*)(Bs + (wc*64 + ni*16 + fr)*64 + kk*32 + fg*8);
    }
    #pragma unroll
    for (int kk = 0; kk < 2; ++kk) {
      #pragma unroll
      for (int mi = 0; mi < 4; ++mi) {
        #pragma unroll
        for (int ni = 0; ni < 4; ++ni)
          acc[mi][ni] = __builtin_amdgcn_mfma_f32_16x16x32_bf16(
              af[kk][mi], bfr[kk][ni], acc[mi][ni], 0, 0, 0);
      }
    }
    __syncthreads();
  }
  #pragma unroll
  for (int mi = 0; mi < 4; ++mi) {
    const int gr = m0 + wr*64 + mi*16 + fg*4;
    #pragma unroll
    for (int ni = 0; ni < 4; ++ni) {
      const int gc = n0 + wc*64 + ni*16 + fr;
      const float bv = bias[gc];
      #pragma unroll
      for (int r = 0; r < 4; ++r) {
        float v = acc[mi][ni][r] + bv;
        size_t off = (size_t)(gr + r) * N + gc;
        if constexpr (OUT_BF16) ((bf16*)C)[off] = __float2bfloat16(v);
        else                    ((float*)C)[off] = v;
      }
    }
  }
}

// ---------------- flash attention, swapped-QK^T in-register softmax --------
// 4 waves x 32 q-rows = 128 q/block; KV tile 64 keys; 32x32x16 MFMA.
// Swapped QK^T: sc = mfma(A=K,B=Q) -> sc[reg]=S[key=crow(reg,hi)][q=l31];
// softmax reduction is lane-local (+1 shfl_xor(32)); P packed to A-frags via
// v_cvt_pk_bf16_f32 + v_permlane32_swap_b32; PV: o = mfma(A=P,B=VT).
// Ks/VTs swizzle: stored chunk = logical ^ S(row), S(row)=(row>>3)^(row&7).
__global__ __launch_bounds__(256) void k_attn(
    const bf16* __restrict__ qkv, const float* __restrict__ gates,
    bf16* __restrict__ combined)
{
  __shared__ __align__(16) bf16 Ks[64 * 64];
  __shared__ __align__(16) bf16 VTs[64 * 64];
  __shared__ float Ltab[128];
  const int id = blockIdx.x;                 // 640 blocks
  const int xcd = id & 7, kgrp = id >> 3;    // kgrp 0..79
  const int qt = kgrp / 10, bel = kgrp - qt * 10;
  const int be = xcd * 10 + bel;
  const int e = be >> 2, b = be & 3;
  const int s0 = qt * 128;
  const int tid = threadIdx.x, wid = tid >> 6, lane = tid & 63;
  const int l31 = lane & 31, hi = lane >> 5;
  const bf16* base = qkv + (size_t)(b * SEQ) * QKV_W + e * QKV_N;
  // Q fragments (B-operand): row s0+wid*32+l31, cols kc*16 + hi*8
  const int rq = s0 + wid * 32 + l31;
  short8 qf[4];
  #pragma unroll
  for (int kc = 0; kc < 4; ++kc)
    qf[kc] = *(const short8*)(base + (size_t)rq * QKV_W + kc*16 + hi*8);
  f32x16 o0 = {}, o1 = {};
  float Mr = -1e30f, Lr = 0.f;
  const float CSC = 0.125f * 1.44269504f;    // SCALE * log2(e)
  for (int c0 = 0; c0 < SEQ; c0 += 64) {
    // --- stage K: linear LDS dest, inverse-swizzled per-lane global src ---
    #pragma unroll
    for (int p = 0; p < 2; ++p) {
      int W = p*4 + wid;
      int row = W*8 + (lane >> 3);
      int g = (lane & 7) ^ W ^ (lane >> 3);   // chunk ^ S(row)
      gload_lds16(base + (size_t)(c0 + row)*QKV_W + 64 + g*8,
                  Ks + (W*64 + lane)*8);
    }
    // --- stage V transposed; chunk swizzled by S(h) ---
    #pragma unroll
    for (int it = 0; it < 2; ++it) {
      int key = it*32 + (tid >> 3);
      int h0b = tid & 7;
      int kc_ = key >> 3, ko = key & 7;
      union { short8 v; bf16 hh[8]; } u;
      u.v = *(const short8*)(base + (size_t)(c0 + key)*QKV_W + 128 + h0b*8);
      #pragma unroll
      for (int j = 0; j < 8; ++j) {
        int scn = kc_ ^ h0b ^ j;
        VTs[(h0b*8 + j)*64 + scn*8 + ko] = u.hh[j];
      }
    }
    __syncthreads();
    #pragma unroll
    for (int s = 0; s < 2; ++s) {
      // --- QK^T swapped ---
      f32x16 sc = {};
      const int krow = s*32 + l31;
      const int Sk = ((krow >> 3) ^ krow) & 7;
      #pragma unroll
      for (int kc = 0; kc < 4; ++kc) {
        int st = (kc*2 + hi) ^ Sk;
        short8 kf = *(const short8*)(Ks + krow*64 + st*8);
        sc = __builtin_amdgcn_mfma_f32_32x32x16_bf16(kf, qf[kc], sc, 0, 0, 0);
      }
      // --- online softmax (lane-local; q = l31) ---
      float m3 = sc[0];
      #pragma unroll
      for (int i = 1; i < 16; ++i) m3 = fmaxf(m3, sc[i]);
      float mx = fmaxf(m3, __shfl_xor(m3, 32)) * CSC;
      if (!__all(mx <= Mr + 8.0f)) {          // rescale event (rare)
        float Mn = fmaxf(Mr, mx);
        float so = exp2f(Mr - Mn);
        Lr *= so; Mr = Mn;
        int soi = __float_as_int(so);
        #pragma unroll
        for (int reg = 0; reg < 16; ++reg) {
          int crow = (reg & 3) + 8*(reg >> 2) + 4*hi;
          float sg = __int_as_float(__builtin_amdgcn_ds_bpermute(crow*4, soi));
          o0[reg] *= sg; o1[reg] *= sg;
        }
      }
      float p[16]; float ls = 0.f;
      #pragma unroll
      for (int i = 0; i < 16; ++i) { p[i] = exp2f(sc[i]*CSC - Mr); ls += p[i]; }
      Lr += ls + __shfl_xor(ls, 32);
      // --- pack P -> PV A-frags: cvt_pk pairs + permlane32_swap ---
      union { int w[4]; short8 v; } pf0, pf1;
      int ta, tb;
      asm("v_cvt_pk_bf16_f32 %0, %1, %2" : "=v"(ta) : "v"(p[0]), "v"(p[1]));
      asm("v_cvt_pk_bf16_f32 %0, %1, %2" : "=v"(tb) : "v"(p[4]), "v"(p[5]));
      asm volatile("v_permlane32_swap_b32 %0, %1" : "+v"(ta), "+v"(tb));
      pf0.w[0] = ta; pf0.w[2] = tb;
      asm("v_cvt_pk_bf16_f32 %0, %1, %2" : "=v"(ta) : "v"(p[2]), "v"(p[3]));
      asm("v_cvt_pk_bf16_f32 %0, %1, %2" : "=v"(tb) : "v"(p[6]), "v"(p[7]));
      asm volatile("v_permlane32_swap_b32 %0, %1" : "+v"(ta), "+v"(tb));
      pf0.w[1] = ta; pf0.w[3] = tb;
      asm("v_cvt_pk_bf16_f32 %0, %1, %2" : "=v"(ta) : "v"(p[8]), "v"(p[9]));
      asm("v_cvt_pk_bf16_f32 %0, %1, %2" : "=v"(tb) : "v"(p[12]), "v"(p[13]));
      asm volatile("v_permlane32_swap_b32 %0, %1" : "+v"(ta), "+v"(tb));
      pf1.w[0] = ta; pf1.w[2] = tb;
      asm("v_cvt_pk_bf16_f32 %0, %1, %2" : "=v"(ta) : "v"(p[10]), "v"(p[11]));
      asm("v_cvt_pk_bf16_f32 %0, %1, %2" : "=v"(tb) : "v"(p[14]), "v"(p[15]));
      asm volatile("v_permlane32_swap_b32 %0, %1" : "+v"(ta), "+v"(tb));
      pf1.w[1] = ta; pf1.w[3] = tb;
      // --- PV: o[hb] += P-frag(kb) x VT-frag(hb,kb) ---
      #pragma unroll
      for (int kb = 0; kb < 2; ++kb) {
        const short8 pv = (kb == 0) ? pf0.v : pf1.v;
        #pragma unroll
        for (int hb = 0; hb < 2; ++hb) {
          int h = hb*32 + l31;
          int cc = (s*4 + kb*2 + hi) ^ (((h >> 3) ^ h) & 7);
          short8 vf = *(const short8*)(VTs + h*64 + cc*8);
          if (hb == 0) o0 = __builtin_amdgcn_mfma_f32_32x32x16_bf16(pv, vf, o0, 0, 0, 0);
          else         o1 = __builtin_amdgcn_mfma_f32_32x32x16_bf16(pv, vf, o1, 0, 0, 0);
        }
      }
    }
    __syncthreads();
  }
  // --- epilogue: fold gate/L, scatter O ---
  if (lane < 32) {
    int q = wid*32 + lane;
    float g = gates[(size_t)(b*SEQ + s0 + q) * NUM_EXPERTS + e];
    Ltab[q] = g / Lr;
  }
  const int rowbase = b*SEQ + s0 + wid*32;
  #pragma unroll
  for (int reg = 0; reg < 16; ++reg) {
    int crow = (reg & 3) + 8*(reg >> 2) + 4*hi;
    float inv = Ltab[wid*32 + crow];
    combined[(size_t)(rowbase + crow)*D_MODEL + e*64 + l31] =
        __float2bfloat16(o0[reg] * inv);
    combined[(size_t)(rowbase + crow)*D_MODEL + e*64 + 32 + l31] =
        __float2bfloat16(o1[reg] * inv);
  }
}

extern "C" void kernel_launch(void* const* d_in, const int* in_sizes, int n_in,
                              void* d_out, int out_size, void* d_ws, size_t ws_size,
                              hipStream_t stream) {
  const float* x    = (const float*)d_in[0];
  const float* wqkv = (const float*)d_in[1];
  const float* bqkv = (const float*)d_in[2];
  const float* rw   = (const float*)d_in[3];
  const float* rb   = (const float*)d_in[4];
  const float* ow   = (const float*)d_in[5];
  const float* ob   = (const float*)d_in[6];
  char* ws = (char*)d_ws;
  bf16*  xb    = (bf16*)(ws);                    // 4096*1280*2      = 10485760
  bf16*  wqkvT = (bf16*)(ws + 10485760);         // [3840][1280] bf16=  9830400
  bf16*  owT   = (bf16*)(ws + 20316160);         // 1280*1280*2      =  3276800
  float* gates = (float*)(ws + 23592960);        // 4096*20*4        =   327680
  bf16*  qkv   = (bf16*)(ws + 23920640);         // [4096][3840] bf16= 31457280
  bf16*  comb  = (bf16*)(ws + 55377920);         // 4096*1280*2      = 10485760
  float* rwT   = (float*)comb;                   // aliased, consumed pre-attn

  k_rwT<<<(D_MODEL * NUM_EXPERTS + 255) / 256, 256, 0, stream>>>(rw, rwT);
  k_gates<<<1024, 256, 0, stream>>>(x, rwT, rb, gates, xb);
  k_transpose<<<dim3(6, 40, 20), dim3(32, 8), 0, stream>>>(wqkv, wqkvT, D_MODEL, QKV_N);
  k_transpose<<<dim3(40, 40, 1), dim3(32, 8), 0, stream>>>(ow, owT, D_MODEL, D_MODEL);
  k_gemm<true><<<8 * 4 * (QKV_W / 128), 256, 0, stream>>>(xb, wqkvT, bqkv, qkv,
                                                          BS_TOK, QKV_W, D_MODEL);
  k_attn<<<640, 256, 0, stream>>>(qkv, gates, comb);
  k_gemm<false><<<8 * 4 * (D_MODEL / 128), 256, 0, stream>>>(comb, owT, ob, d_out,
                                                             BS_TOK, D_MODEL, D_MODEL);
}

// Round 7
// 181.223 us; speedup vs baseline: 1.2820x; 1.1210x over previous
//
#include <hip/hip_runtime.h>
#include <hip/hip_bf16.h>

#define D_MODEL 1280
#define NUM_EXPERTS 20
#define HEAD_DIM 64
#define SEQ 1024
#define BATCH 4
#define BS_TOK 4096
#define QKV_N 192
#define QKV_W 3840   // 20 experts * 192, flat qkv row width

typedef __attribute__((ext_vector_type(8))) short short8;
typedef __attribute__((ext_vector_type(4))) float f32x4;
typedef __attribute__((ext_vector_type(16))) float f32x16;
typedef __hip_bfloat16 bf16;

static __device__ __forceinline__ void gload_lds16(const void* g, void* l) {
  __builtin_amdgcn_global_load_lds((const __attribute__((address_space(1))) void*)g,
                                   (__attribute__((address_space(3))) void*)l, 16, 0, 0);
}

// ---------------- router_w [D][E] f32 -> rwT [E][D] f32 ----------------
__global__ __launch_bounds__(256) void k_rwT(const float* __restrict__ in,
                                             float* __restrict__ out) {
  int i = blockIdx.x * 256 + threadIdx.x;
  if (i < D_MODEL * NUM_EXPERTS) {
    int d = i / NUM_EXPERTS, e = i % NUM_EXPERTS;
    out[e * D_MODEL + d] = in[i];
  }
}

// ---------------- router gates + x -> bf16 (4 rows/block, wave per row) ----
__global__ __launch_bounds__(256) void k_gates(const float* __restrict__ x,
    const float* __restrict__ rwT, const float* __restrict__ rb,
    float* __restrict__ gates, bf16* __restrict__ xb)
{
  __shared__ float xs[4][D_MODEL];
  __shared__ float logits[4][NUM_EXPERTS];
  const int r0 = blockIdx.x * 4;
  for (int i = threadIdx.x; i < 4 * (D_MODEL / 2); i += 256) {
    int r = i / (D_MODEL / 2), d2 = (i % (D_MODEL / 2)) * 2;
    float2 v = *(const float2*)(x + (size_t)(r0 + r) * D_MODEL + d2);
    xs[r][d2] = v.x; xs[r][d2 + 1] = v.y;
    __hip_bfloat162 h;
    h.x = __float2bfloat16(v.x); h.y = __float2bfloat16(v.y);
    *(__hip_bfloat162*)(xb + (size_t)(r0 + r) * D_MODEL + d2) = h;
  }
  __syncthreads();
  const int wid = threadIdx.x >> 6, lane = threadIdx.x & 63;
  for (int e = 0; e < NUM_EXPERTS; ++e) {
    float s = 0.f;
    #pragma unroll
    for (int j = 0; j < D_MODEL / 64; ++j) {
      int d = lane + 64 * j;
      s += xs[wid][d] * rwT[e * D_MODEL + d];
    }
    #pragma unroll
    for (int m = 32; m >= 1; m >>= 1) s += __shfl_xor(s, m);
    if (lane == 0) logits[wid][e] = s + rb[e];
  }
  __syncthreads();
  if (lane < 32) {
    float v = (lane < NUM_EXPERTS) ? logits[wid][lane] : -1e30f;
    float mx = v;
    #pragma unroll
    for (int m = 16; m >= 1; m >>= 1) mx = fmaxf(mx, __shfl_xor(mx, m, 32));
    float p = (lane < NUM_EXPERTS) ? __expf(v - mx) : 0.f;
    float sum = p;
    #pragma unroll
    for (int m = 16; m >= 1; m >>= 1) sum += __shfl_xor(sum, m, 32);
    if (lane < NUM_EXPERTS)
      gates[(size_t)(r0 + wid) * NUM_EXPERTS + lane] = p / sum;
  }
}

// ---------------- f32 [batch][R][C] -> bf16 [batch][C][R] ----------------
__global__ __launch_bounds__(256) void k_transpose(const float* __restrict__ in,
    bf16* __restrict__ out, int R, int C)
{
  __shared__ float tile[32][33];
  const size_t bo = (size_t)blockIdx.z * R * C;
  const int c0 = blockIdx.x * 32, r0 = blockIdx.y * 32;
  const int tx = threadIdx.x, ty = threadIdx.y;  // block (32,8)
  #pragma unroll
  for (int i = 0; i < 4; ++i)
    tile[ty + 8*i][tx] = in[bo + (size_t)(r0 + ty + 8*i) * C + (c0 + tx)];
  __syncthreads();
  #pragma unroll
  for (int i = 0; i < 4; ++i)
    out[bo + (size_t)(c0 + ty + 8*i) * R + (r0 + tx)] =
        __float2bfloat16(tile[tx][ty + 8*i]);
}

// ======= 256x256 bf16 GEMM, BK=32, 4-deep LDS ring, counted vmcnt =========
// C = A @ BT^T + bias (bf16 out). 512 threads = 8 waves (2M x 4N), per-wave
// output 128x64 (8x4 16x16 frags). LDS 4 bufs x (A 256x32 + B 256x32) =128KB.
// Swizzle: stored chunk slot = logical ^ (row&3); staged via inverse-swizzled
// global source (gload_lds dest stays linear), read with same XOR.
// Steady state: stage tile t+3 during compute of t; wait vmcnt(8) per iter
// (tiles t+2,t+3 in flight) -> never drains until tail.
__global__ __launch_bounds__(512, 2) void k_gemm256(
    const bf16* __restrict__ A, const bf16* __restrict__ BT,
    const float* __restrict__ bias, bf16* __restrict__ C,
    int M, int N, int K)
{
  __shared__ __align__(16) bf16 lds[4][2][256 * 32];
  const int bid = blockIdx.x;
  const int xcd = bid & 7, c = bid >> 3;        // 240 = 8 * 30
  const int m0 = (xcd * 2 + (c & 1)) * 256;     // 16 m-panels
  const int n0 = (c >> 1) * 256;                // 15 n-panels
  const int tid = threadIdx.x, wid = tid >> 6, lane = tid & 63;
  const int wr = wid >> 2, wcn = wid & 3;
  const int fr = lane & 15, fg = lane >> 4;
  const int nt = K / 32;                        // 40 K-tiles

  auto STAGE = [&](int t, int buf) {
    const bf16* Ag = A + (size_t)m0 * K + t * 32;
    const bf16* Bg = BT + (size_t)n0 * K + t * 32;
    #pragma unroll
    for (int i = 0; i < 2; ++i) {
      int idx = i * 512 + tid;
      int row = idx >> 2, sc = idx & 3;
      int g = sc ^ (row & 3);
      gload_lds16(Ag + (size_t)row * K + g * 8, &lds[buf][0][idx * 8]);
    }
    #pragma unroll
    for (int i = 0; i < 2; ++i) {
      int idx = i * 512 + tid;
      int row = idx >> 2, sc = idx & 3;
      int g = sc ^ (row & 3);
      gload_lds16(Bg + (size_t)row * K + g * 8, &lds[buf][1][idx * 8]);
    }
  };

  f32x4 acc[8][4] = {};
  auto COMPUTE = [&](int buf) {
    const bf16* As_ = &lds[buf][0][0];
    const bf16* Bs_ = &lds[buf][1][0];
    short8 af[8], bfv[4];
    #pragma unroll
    for (int mi = 0; mi < 8; ++mi) {
      int row = wr * 128 + mi * 16 + fr;
      int slot = fg ^ (row & 3);
      af[mi] = *(const short8*)(As_ + row * 32 + slot * 8);
    }
    #pragma unroll
    for (int ni = 0; ni < 4; ++ni) {
      int row = wcn * 64 + ni * 16 + fr;
      int slot = fg ^ (row & 3);
      bfv[ni] = *(const short8*)(Bs_ + row * 32 + slot * 8);
    }
    __builtin_amdgcn_s_setprio(1);
    #pragma unroll
    for (int mi = 0; mi < 8; ++mi) {
      #pragma unroll
      for (int ni = 0; ni < 4; ++ni)
        acc[mi][ni] = __builtin_amdgcn_mfma_f32_16x16x32_bf16(
            af[mi], bfv[ni], acc[mi][ni], 0, 0, 0);
    }
    __builtin_amdgcn_s_setprio(0);
  };

  // prologue: stage tiles 0,1,2; wait tile 0 (8 outstanding allowed)
  STAGE(0, 0); STAGE(1, 1); STAGE(2, 2);
  asm volatile("s_waitcnt vmcnt(8)" ::: "memory");
  __builtin_amdgcn_s_barrier();
  __builtin_amdgcn_sched_barrier(0);
  int buf = 0;
  for (int t = 0; t < nt - 3; ++t) {
    int nb = buf + 3; nb = (nb >= 4) ? nb - 4 : nb;
    STAGE(t + 3, nb);
    COMPUTE(buf);
    asm volatile("s_waitcnt vmcnt(8)" ::: "memory");   // t+1 complete
    __builtin_amdgcn_s_barrier();
    __builtin_amdgcn_sched_barrier(0);
    buf = (buf == 3) ? 0 : buf + 1;
  }
  COMPUTE(buf);                                        // t = nt-3
  asm volatile("s_waitcnt vmcnt(4)" ::: "memory");     // nt-2 complete
  __builtin_amdgcn_s_barrier();
  __builtin_amdgcn_sched_barrier(0);
  buf = (buf == 3) ? 0 : buf + 1;
  COMPUTE(buf);                                        // t = nt-2
  asm volatile("s_waitcnt vmcnt(0)" ::: "memory");     // nt-1 complete
  __builtin_amdgcn_s_barrier();
  __builtin_amdgcn_sched_barrier(0);
  buf = (buf == 3) ? 0 : buf + 1;
  COMPUTE(buf);                                        // t = nt-1

  #pragma unroll
  for (int mi = 0; mi < 8; ++mi) {
    const int gr = m0 + wr * 128 + mi * 16 + fg * 4;
    #pragma unroll
    for (int ni = 0; ni < 4; ++ni) {
      const int gc = n0 + wcn * 64 + ni * 16 + fr;
      const float bv = bias[gc];
      #pragma unroll
      for (int r = 0; r < 4; ++r)
        C[(size_t)(gr + r) * N + gc] = __float2bfloat16(acc[mi][ni][r] + bv);
    }
  }
}

// ------- bf16 MFMA GEMM, 128x128 tile (out-projection) ---------------------
template<bool OUT_BF16>
__global__ __launch_bounds__(256) void k_gemm(
    const bf16* __restrict__ A, const bf16* __restrict__ BT,
    const float* __restrict__ bias, void* __restrict__ C,
    int M, int N, int K)
{
  __shared__ __align__(16) bf16 As[128 * 64];
  __shared__ __align__(16) bf16 Bs[128 * 64];
  const int bid = blockIdx.x;
  const int xcd = bid & 7, c = bid >> 3;
  const int m0 = (xcd * 4 + (c & 3)) * 128;
  const int n0 = (c >> 2) * 128;
  const int tid = threadIdx.x, wid = tid >> 6, lane = tid & 63;
  const int wr = wid >> 1, wc = wid & 1;
  const int fr = lane & 15, fg = lane >> 4;
  f32x4 acc[4][4] = {};
  for (int k0 = 0; k0 < K; k0 += 64) {
    #pragma unroll
    for (int p = 0; p < 4; ++p) {
      int eidx = ((p*4 + wid)*64 + lane) * 8;
      int row = eidx >> 6, col = eidx & 63;
      gload_lds16(A + (size_t)(m0 + row)*K + k0 + col, As + eidx);
      gload_lds16(BT + (size_t)(n0 + row)*K + k0 + col, Bs + eidx);
    }
    __syncthreads();
    short8 af[2][4], bfr[2][4];
    #pragma unroll
    for (int kk = 0; kk < 2; ++kk) {
      #pragma unroll
      for (int mi = 0; mi < 4; ++mi)
        af[kk][mi] = *(const short8*)(As + (wr*64 + mi*16 + fr)*64 + kk*32 + fg*8);
      #pragma unroll
      for (int ni = 0; ni < 4; ++ni)
        bfr[kk][ni] = *(const short8*)(Bs + (wc*64 + ni*16 + fr)*64 + kk*32 + fg*8);
    }
    #pragma unroll
    for (int kk = 0; kk < 2; ++kk) {
      #pragma unroll
      for (int mi = 0; mi < 4; ++mi) {
        #pragma unroll
        for (int ni = 0; ni < 4; ++ni)
          acc[mi][ni] = __builtin_amdgcn_mfma_f32_16x16x32_bf16(
              af[kk][mi], bfr[kk][ni], acc[mi][ni], 0, 0, 0);
      }
    }
    __syncthreads();
  }
  #pragma unroll
  for (int mi = 0; mi < 4; ++mi) {
    const int gr = m0 + wr*64 + mi*16 + fg*4;
    #pragma unroll
    for (int ni = 0; ni < 4; ++ni) {
      const int gc = n0 + wc*64 + ni*16 + fr;
      const float bv = bias[gc];
      #pragma unroll
      for (int r = 0; r < 4; ++r) {
        float v = acc[mi][ni][r] + bv;
        size_t off = (size_t)(gr + r) * N + gc;
        if constexpr (OUT_BF16) ((bf16*)C)[off] = __float2bfloat16(v);
        else                    ((float*)C)[off] = v;
      }
    }
  }
}

// ---------------- flash attention, swapped-QK^T in-register softmax --------
__global__ __launch_bounds__(256) void k_attn(
    const bf16* __restrict__ qkv, const float* __restrict__ gates,
    bf16* __restrict__ combined)
{
  __shared__ __align__(16) bf16 Ks[64 * 64];
  __shared__ __align__(16) bf16 VTs[64 * 64];
  __shared__ float Ltab[128];
  const int id = blockIdx.x;                 // 640 blocks
  const int xcd = id & 7, kgrp = id >> 3;    // kgrp 0..79
  const int qt = kgrp / 10, bel = kgrp - qt * 10;
  const int be = xcd * 10 + bel;
  const int e = be >> 2, b = be & 3;
  const int s0 = qt * 128;
  const int tid = threadIdx.x, wid = tid >> 6, lane = tid & 63;
  const int l31 = lane & 31, hi = lane >> 5;
  const bf16* base = qkv + (size_t)(b * SEQ) * QKV_W + e * QKV_N;
  const int rq = s0 + wid * 32 + l31;
  short8 qf[4];
  #pragma unroll
  for (int kc = 0; kc < 4; ++kc)
    qf[kc] = *(const short8*)(base + (size_t)rq * QKV_W + kc*16 + hi*8);
  f32x16 o0 = {}, o1 = {};
  float Mr = -1e30f, Lr = 0.f;
  const float CSC = 0.125f * 1.44269504f;    // SCALE * log2(e)
  for (int c0 = 0; c0 < SEQ; c0 += 64) {
    #pragma unroll
    for (int p = 0; p < 2; ++p) {
      int W = p*4 + wid;
      int row = W*8 + (lane >> 3);
      int g = (lane & 7) ^ W ^ (lane >> 3);   // chunk ^ S(row)
      gload_lds16(base + (size_t)(c0 + row)*QKV_W + 64 + g*8,
                  Ks + (W*64 + lane)*8);
    }
    #pragma unroll
    for (int it = 0; it < 2; ++it) {
      int key = it*32 + (tid >> 3);
      int h0b = tid & 7;
      int kc_ = key >> 3, ko = key & 7;
      union { short8 v; bf16 hh[8]; } u;
      u.v = *(const short8*)(base + (size_t)(c0 + key)*QKV_W + 128 + h0b*8);
      #pragma unroll
      for (int j = 0; j < 8; ++j) {
        int scn = kc_ ^ h0b ^ j;
        VTs[(h0b*8 + j)*64 + scn*8 + ko] = u.hh[j];
      }
    }
    __syncthreads();
    #pragma unroll
    for (int s = 0; s < 2; ++s) {
      f32x16 sc = {};
      const int krow = s*32 + l31;
      const int Sk = ((krow >> 3) ^ krow) & 7;
      #pragma unroll
      for (int kc = 0; kc < 4; ++kc) {
        int st = (kc*2 + hi) ^ Sk;
        short8 kf = *(const short8*)(Ks + krow*64 + st*8);
        sc = __builtin_amdgcn_mfma_f32_32x32x16_bf16(kf, qf[kc], sc, 0, 0, 0);
      }
      float m3 = sc[0];
      #pragma unroll
      for (int i = 1; i < 16; ++i) m3 = fmaxf(m3, sc[i]);
      float mx = fmaxf(m3, __shfl_xor(m3, 32)) * CSC;
      if (!__all(mx <= Mr + 8.0f)) {          // rescale event (rare)
        float Mn = fmaxf(Mr, mx);
        float so = exp2f(Mr - Mn);
        Lr *= so; Mr = Mn;
        int soi = __float_as_int(so);
        #pragma unroll
        for (int reg = 0; reg < 16; ++reg) {
          int crow = (reg & 3) + 8*(reg >> 2) + 4*hi;
          float sg = __int_as_float(__builtin_amdgcn_ds_bpermute(crow*4, soi));
          o0[reg] *= sg; o1[reg] *= sg;
        }
      }
      float p[16]; float ls = 0.f;
      #pragma unroll
      for (int i = 0; i < 16; ++i) { p[i] = exp2f(sc[i]*CSC - Mr); ls += p[i]; }
      Lr += ls + __shfl_xor(ls, 32);
      union { int w[4]; short8 v; } pf0, pf1;
      int ta, tb;
      asm("v_cvt_pk_bf16_f32 %0, %1, %2" : "=v"(ta) : "v"(p[0]), "v"(p[1]));
      asm("v_cvt_pk_bf16_f32 %0, %1, %2" : "=v"(tb) : "v"(p[4]), "v"(p[5]));
      asm volatile("v_permlane32_swap_b32 %0, %1" : "+v"(ta), "+v"(tb));
      pf0.w[0] = ta; pf0.w[2] = tb;
      asm("v_cvt_pk_bf16_f32 %0, %1, %2" : "=v"(ta) : "v"(p[2]), "v"(p[3]));
      asm("v_cvt_pk_bf16_f32 %0, %1, %2" : "=v"(tb) : "v"(p[6]), "v"(p[7]));
      asm volatile("v_permlane32_swap_b32 %0, %1" : "+v"(ta), "+v"(tb));
      pf0.w[1] = ta; pf0.w[3] = tb;
      asm("v_cvt_pk_bf16_f32 %0, %1, %2" : "=v"(ta) : "v"(p[8]), "v"(p[9]));
      asm("v_cvt_pk_bf16_f32 %0, %1, %2" : "=v"(tb) : "v"(p[12]), "v"(p[13]));
      asm volatile("v_permlane32_swap_b32 %0, %1" : "+v"(ta), "+v"(tb));
      pf1.w[0] = ta; pf1.w[2] = tb;
      asm("v_cvt_pk_bf16_f32 %0, %1, %2" : "=v"(ta) : "v"(p[10]), "v"(p[11]));
      asm("v_cvt_pk_bf16_f32 %0, %1, %2" : "=v"(tb) : "v"(p[14]), "v"(p[15]));
      asm volatile("v_permlane32_swap_b32 %0, %1" : "+v"(ta), "+v"(tb));
      pf1.w[1] = ta; pf1.w[3] = tb;
      #pragma unroll
      for (int kb = 0; kb < 2; ++kb) {
        const short8 pv = (kb == 0) ? pf0.v : pf1.v;
        #pragma unroll
        for (int hb = 0; hb < 2; ++hb) {
          int h = hb*32 + l31;
          int cc = (s*4 + kb*2 + hi) ^ (((h >> 3) ^ h) & 7);
          short8 vf = *(const short8*)(VTs + h*64 + cc*8);
          if (hb == 0) o0 = __builtin_amdgcn_mfma_f32_32x32x16_bf16(pv, vf, o0, 0, 0, 0);
          else         o1 = __builtin_amdgcn_mfma_f32_32x32x16_bf16(pv, vf, o1, 0, 0, 0);
        }
      }
    }
    __syncthreads();
  }
  if (lane < 32) {
    int q = wid*32 + lane;
    float g = gates[(size_t)(b*SEQ + s0 + q) * NUM_EXPERTS + e];
    Ltab[q] = g / Lr;
  }
  const int rowbase = b*SEQ + s0 + wid*32;
  #pragma unroll
  for (int reg = 0; reg < 16; ++reg) {
    int crow = (reg & 3) + 8*(reg >> 2) + 4*hi;
    float inv = Ltab[wid*32 + crow];
    combined[(size_t)(rowbase + crow)*D_MODEL + e*64 + l31] =
        __float2bfloat16(o0[reg] * inv);
    combined[(size_t)(rowbase + crow)*D_MODEL + e*64 + 32 + l31] =
        __float2bfloat16(o1[reg] * inv);
  }
}

extern "C" void kernel_launch(void* const* d_in, const int* in_sizes, int n_in,
                              void* d_out, int out_size, void* d_ws, size_t ws_size,
                              hipStream_t stream) {
  const float* x    = (const float*)d_in[0];
  const float* wqkv = (const float*)d_in[1];
  const float* bqkv = (const float*)d_in[2];
  const float* rw   = (const float*)d_in[3];
  const float* rb   = (const float*)d_in[4];
  const float* ow   = (const float*)d_in[5];
  const float* ob   = (const float*)d_in[6];
  char* ws = (char*)d_ws;
  bf16*  xb    = (bf16*)(ws);                    // 4096*1280*2      = 10485760
  bf16*  wqkvT = (bf16*)(ws + 10485760);         // [3840][1280] bf16=  9830400
  bf16*  owT   = (bf16*)(ws + 20316160);         // 1280*1280*2      =  3276800
  float* gates = (float*)(ws + 23592960);        // 4096*20*4        =   327680
  bf16*  qkv   = (bf16*)(ws + 23920640);         // [4096][3840] bf16= 31457280
  bf16*  comb  = (bf16*)(ws + 55377920);         // 4096*1280*2      = 10485760
  float* rwT   = (float*)comb;                   // aliased, consumed pre-attn

  k_rwT<<<(D_MODEL * NUM_EXPERTS + 255) / 256, 256, 0, stream>>>(rw, rwT);
  k_gates<<<1024, 256, 0, stream>>>(x, rwT, rb, gates, xb);
  k_transpose<<<dim3(6, 40, 20), dim3(32, 8), 0, stream>>>(wqkv, wqkvT, D_MODEL, QKV_N);
  k_transpose<<<dim3(40, 40, 1), dim3(32, 8), 0, stream>>>(ow, owT, D_MODEL, D_MODEL);
  k_gemm256<<<240, 512, 0, stream>>>(xb, wqkvT, bqkv, qkv, BS_TOK, QKV_W, D_MODEL);
  k_attn<<<640, 256, 0, stream>>>(qkv, gates, comb);
  k_gemm<false><<<8 * 4 * (D_MODEL / 128), 256, 0, stream>>>(comb, owT, ob, d_out,
                                                             BS_TOK, D_MODEL, D_MODEL);
}